// Round 11
// baseline (348.460 us; speedup 1.0000x reference)
//
#include <hip/hip_runtime.h>
#include <cstdint>
#include <cstddef>

#define E_EXP 8
#define LDIM 1024
#define ODIM 1024
#define NPAIR 64            // key = lo*8+hi, lo<hi (<=28 nonempty)

// ---- pair-grouped GEMM geometry: 256x128 tile, K=1024 over TWO experts ----
#define BM 256
#define BN 128
#define BK 32
#define NKT (LDIM / BK)     // 32 K-tiles
#define MAXRT 160           // sum ceil(cnt/256) <= 32768/256 + 28 = 156
#define GEMM_GRID (MAXRT * 8)  // 1280 = 8 * 160 (8 col tiles)
#define CPX (GEMM_GRID / 8)    // 160 per XCD chunk

typedef __bf16 bf16x8 __attribute__((ext_vector_type(8)));
typedef float f32x4 __attribute__((ext_vector_type(4)));

__device__ __forceinline__ unsigned short f2bf(float f) {
  uint32_t u = __float_as_uint(f);
  u += 0x7FFFu + ((u >> 16) & 1u);   // round-to-nearest-even
  return (unsigned short)(u >> 16);
}

__device__ __forceinline__ void gload_lds16(const void* g, void* l) {
  __builtin_amdgcn_global_load_lds(
      (const __attribute__((address_space(1))) unsigned int*)g,
      (__attribute__((address_space(3))) unsigned int*)l, 16, 0, 0);
}

// ---------------- routing + x->bf16 conversion: 4 tokens per wave ----------------
__global__ __launch_bounds__(256) void route_kernel(
    const float* __restrict__ x, const float* __restrict__ gate,
    unsigned short* __restrict__ xb, int* __restrict__ sel,
    float2* __restrict__ pw, int T)
{
  const int wid = threadIdx.x >> 6, lane = threadIdx.x & 63;
  const int tokBase = blockIdx.x * 16 + wid * 4;
  if (tokBase >= T) return;
  const float* xr = x + (size_t)tokBase * LDIM;
  unsigned short* xbr = xb + (size_t)tokBase * LDIM;

  float acc[4][E_EXP];
#pragma unroll
  for (int j = 0; j < 4; ++j)
#pragma unroll
    for (int e = 0; e < E_EXP; ++e) acc[j][e] = 0.f;

#pragma unroll
  for (int it = 0; it < 4; ++it) {
    const int c = it * 256 + lane * 4;
    float4 xv[4];
#pragma unroll
    for (int j = 0; j < 4; ++j) {
      xv[j] = *(const float4*)(xr + (size_t)j * LDIM + c);
      ushort4 bv;
      bv.x = f2bf(xv[j].x); bv.y = f2bf(xv[j].y);
      bv.z = f2bf(xv[j].z); bv.w = f2bf(xv[j].w);
      *(ushort4*)(xbr + (size_t)j * LDIM + c) = bv;
    }
#pragma unroll
    for (int e = 0; e < E_EXP; ++e) {
      float4 gv = *(const float4*)(gate + e * LDIM + c);
#pragma unroll
      for (int j = 0; j < 4; ++j)
        acc[j][e] += xv[j].x * gv.x + xv[j].y * gv.y + xv[j].z * gv.z + xv[j].w * gv.w;
    }
  }
#pragma unroll
  for (int off = 32; off >= 1; off >>= 1) {
#pragma unroll
    for (int j = 0; j < 4; ++j)
#pragma unroll
      for (int e = 0; e < E_EXP; ++e) acc[j][e] += __shfl_xor(acc[j][e], off, 64);
  }
  if (lane < 4) {
    const int tok = tokBase + lane;
    if (tok < T) {
      float lg[E_EXP];
#pragma unroll
      for (int e = 0; e < E_EXP; ++e) lg[e] = acc[lane][e];
      int i1 = 0; float m1 = lg[0];
#pragma unroll
      for (int e = 1; e < E_EXP; ++e) if (lg[e] > m1) { m1 = lg[e]; i1 = e; }
      int i2 = -1; float m2 = -1e30f;
#pragma unroll
      for (int e = 0; e < E_EXP; ++e) if (e != i1 && lg[e] > m2) { m2 = lg[e]; i2 = e; }
      float s = 0.f;
#pragma unroll
      for (int e = 0; e < E_EXP; ++e) s += __expf(lg[e] - m1);
      const float inv = 1.f / s;
      sel[tok] = i1 | (i2 << 4);
      pw[tok] = make_float2(inv, __expf(m2 - m1) * inv);
    }
  }
}

// ---------------- per-block pair histogram (NO global atomics) ----------------
__global__ __launch_bounds__(256) void hist_kernel(
    const int* __restrict__ sel, int* __restrict__ hist2d, int T)
{
  __shared__ int h[NPAIR];
  const int tid = threadIdx.x;
  if (tid < NPAIR) h[tid] = 0;
  __syncthreads();
  const int t0 = blockIdx.x * 2048;
#pragma unroll
  for (int i = 0; i < 8; ++i) {
    const int t = t0 + i * 256 + tid;
    if (t < T) {
      const int s = sel[t];
      const int i1 = s & 15, i2 = (s >> 4) & 15;
      const int lo = i1 < i2 ? i1 : i2, hi = i1 < i2 ? i2 : i1;
      atomicAdd(&h[lo * 8 + hi], 1);
    }
  }
  __syncthreads();
  if (tid < NPAIR) hist2d[blockIdx.x * NPAIR + tid] = h[tid];
}

// ---------------- prefix sums + row-tile descriptors (parallel over pairs) ----
__global__ void finalize_kernel(
    const int* __restrict__ hist2d, int nb,
    int* __restrict__ blockBase, int4* __restrict__ desc, int* __restrict__ meta)
{
  __shared__ int pcnt[NPAIR], pbase[NPAIR];
  const int p = threadIdx.x;
  if (p < NPAIR) {
    int c = 0;
#pragma unroll 4
    for (int b = 0; b < nb; ++b) c += hist2d[b * NPAIR + p];
    pcnt[p] = c;
  }
  __syncthreads();
  if (p == 0) {
    int s = 0;
    for (int q = 0; q < NPAIR; ++q) { pbase[q] = s; s += pcnt[q]; }
  }
  __syncthreads();
  if (p < NPAIR) {
    int run = pbase[p];
    for (int b = 0; b < nb; ++b) {
      blockBase[b * NPAIR + p] = run;
      run += hist2d[b * NPAIR + p];
    }
  }
  if (p == 0) {
    int rt = 0;
    for (int q = 0; q < NPAIR; ++q) {
      const int lo = q >> 3, hi = q & 7;
      for (int j = 0; j * BM < pcnt[q]; ++j) {
        int rows = pcnt[q] - j * BM; if (rows > BM) rows = BM;
        desc[rt] = make_int4(lo | (hi << 8), pbase[q] + j * BM, rows, 0);
        ++rt;
      }
    }
    meta[0] = rt;
  }
}

// ---------------- deterministic scatter into compact pair lists ----------------
__global__ __launch_bounds__(256) void scatter_kernel(
    const int* __restrict__ sel, const float2* __restrict__ pw,
    const int* __restrict__ blockBase, int* __restrict__ tokC,
    float2* __restrict__ wC, int T)
{
  __shared__ int cur[NPAIR];
  const int tid = threadIdx.x;
  if (tid < NPAIR) cur[tid] = blockBase[blockIdx.x * NPAIR + tid];
  __syncthreads();
  const int t0 = blockIdx.x * 2048;
#pragma unroll
  for (int i = 0; i < 8; ++i) {
    const int t = t0 + i * 256 + tid;
    if (t < T) {
      const int s = sel[t];
      const int i1 = s & 15, i2 = (s >> 4) & 15;
      const float2 w = pw[t];
      const int lo = i1 < i2 ? i1 : i2, hi = i1 < i2 ? i2 : i1;
      const float wlo = i1 < i2 ? w.x : w.y;
      const float whi = i1 < i2 ? w.y : w.x;
      const int pos = atomicAdd(&cur[lo * 8 + hi], 1);   // LDS atomic only
      tokC[pos] = t;
      wC[pos] = make_float2(wlo, whi);
    }
  }
}

// ---------------- expert_w -> bf16 ----------------
__global__ __launch_bounds__(256) void convw_kernel(
    const float* __restrict__ w, unsigned short* __restrict__ wb, int n4)
{
  int i = blockIdx.x * 256 + threadIdx.x;
  if (i >= n4) return;
  float4 v = *(const float4*)(w + (size_t)i * 4);
  ushort4 b;
  b.x = f2bf(v.x); b.y = f2bf(v.y); b.z = f2bf(v.z); b.w = f2bf(v.w);
  *(ushort4*)(wb + (size_t)i * 4) = b;
}

// ---------------- pair-grouped gathered GEMM: 256x128, two experts, store-once ----
// R8 16x16x32 body with B MOVED OUT OF LDS: B fragments are loaded straight
// from global (L2/L3-resident weight panels) into registers, prefetched one
// K-tile ahead (registers are private -> no barrier/publish hazard, unlike the
// failed LDS-frag prefetch). LDS now holds A only (3-ring, 48KB): LDS traffic
// drops 96->64 KB per K-tile per CU (the binding pipe), ds_reads 12->8.
// body t: ds_read A(t) x8 | stage A(t+2) (2 gload_lds) | MFMA x32 w/ B(t) regs
//         | issue 4 global b128 -> B(t+1) | lgkm(0) | vmcnt(6) | barrier.
// vmcnt(6) leaves {stageA(t+2):2, B(t+1):4} in flight, certifies stageA(t+1);
// compiler inserts its own counted vmcnt for the B register deps.
__global__ __launch_bounds__(512, 2) void moe_gemm_pair(
    const unsigned short* __restrict__ xb, const unsigned short* __restrict__ wb,
    const float* __restrict__ bias, const int4* __restrict__ desc,
    const int* __restrict__ meta, const int* __restrict__ tokC,
    const float2* __restrict__ wC, float* __restrict__ out)
{
  __shared__ __align__(16) unsigned short ldsA[3][BM * BK];       // 3 x 16KB
  const int tid = threadIdx.x;
  const int lane = tid & 63, w = tid >> 6;
  const int wm = w >> 2, wn = w & 3;   // 2(M) x 4(N); per-wave out 128 x 32 per expert

  const int totalRT = meta[0];
  const int swz = ((int)blockIdx.x & 7) * CPX + ((int)blockIdx.x >> 3);
  if (swz >= totalRT * 8) return;
  const int rt = swz >> 3, colTile = swz & 7;
  const int4 d = desc[rt];
  const int lo = d.x & 255, hi = d.x >> 8;
  const int start = d.y, ce = d.z;
  const int* tokL = tokC + start;
  const float2* wgtL = wC + start;

  // ---- A staging sources (16B granule s of rows; source pre-swizzled) ----
  const int s = lane & 3;
  const int rA0 = w * 32 + (lane >> 2);
  const int rA1 = rA0 + 16;
  const int gA0 = s ^ ((rA0 >> 1) & 3);
  const int gA1 = s ^ ((rA1 >> 1) & 3);
  const int tA0 = tokL[rA0 < ce ? rA0 : ce - 1];
  const int tA1 = tokL[rA1 < ce ? rA1 : ce - 1];
  const char* aSrc0 = (const char*)(xb + (size_t)tA0 * LDIM) + gA0 * 16;
  const char* aSrc1 = (const char*)(xb + (size_t)tA1 * LDIM) + gA1 * 16;

  // ---- B per-lane global fragment pointers (MFMA layout direct) ----
  // frag fc of expert e at tile kt: ptr + fc*16*LDIM + kt*32 (shorts)
  const unsigned short* bPL =
      wb + ((size_t)lo * ODIM + colTile * BN + wn * 32 + (lane & 15)) * LDIM + (lane >> 4) * 8;
  const unsigned short* bPH =
      wb + ((size_t)hi * ODIM + colTile * BN + wn * 32 + (lane & 15)) * LDIM + (lane >> 4) * 8;

  // ---- A ds_read offsets (shorts) ----
  int offA[8];
#pragma unroll
  for (int fr = 0; fr < 8; ++fr) {
    const int r = wm * 128 + fr * 16 + (lane & 15);
    offA[fr] = r * BK + (((lane >> 4) ^ ((r >> 1) & 3)) * 8);
  }

  auto stage = [&](int b, int kt) {
    const int kb = kt * 64;  // bytes
    gload_lds16(aSrc0 + kb, &ldsA[b][w * 1024]);
    gload_lds16(aSrc1 + kb, &ldsA[b][w * 1024 + 512]);
  };

  f32x4 acc[2][8][2] = {};

  auto mfmaCl = [&](bf16x8 (&af)[8], bf16x8 (&bl)[2], bf16x8 (&bh)[2]) {
#pragma unroll
    for (int fr = 0; fr < 8; ++fr) {
      acc[0][fr][0] = __builtin_amdgcn_mfma_f32_16x16x32_bf16(af[fr], bl[0], acc[0][fr][0], 0, 0, 0);
      acc[0][fr][1] = __builtin_amdgcn_mfma_f32_16x16x32_bf16(af[fr], bl[1], acc[0][fr][1], 0, 0, 0);
      acc[1][fr][0] = __builtin_amdgcn_mfma_f32_16x16x32_bf16(af[fr], bh[0], acc[1][fr][0], 0, 0, 0);
      acc[1][fr][1] = __builtin_amdgcn_mfma_f32_16x16x32_bf16(af[fr], bh[1], acc[1][fr][1], 0, 0, 0);
    }
  };
  auto loadB = [&](int kt, bf16x8 (&bl)[2], bf16x8 (&bh)[2]) {
    bl[0] = *(const bf16x8*)(bPL + kt * 32);
    bl[1] = *(const bf16x8*)(bPL + 16 * LDIM + kt * 32);
    bh[0] = *(const bf16x8*)(bPH + kt * 32);
    bh[1] = *(const bf16x8*)(bPH + 16 * LDIM + kt * 32);
  };

  bf16x8 blA[2], bhA[2], blB[2], bhB[2];

  // ---- prologue: stage A tiles 0,1; load B(0); certify stage 0 ----
  stage(0, 0); stage(1, 1);
  loadB(0, blA, bhA);
  asm volatile("s_waitcnt vmcnt(6)" ::: "memory");   // stage A(0) complete
  __builtin_amdgcn_s_barrier();

  int buf = 0;
#define GEMM_BODY(T_, BLc, BHc, BLn, BHn)                                    \
  {                                                                          \
    const unsigned short* As = &ldsA[buf][0];                                \
    bf16x8 af[8];                                                            \
    _Pragma("unroll")                                                        \
    for (int fr = 0; fr < 8; ++fr) af[fr] = *(const bf16x8*)(As + offA[fr]); \
    int sb = buf + 2; if (sb > 2) sb -= 3;                                   \
    stage(sb, (T_) + 2 < NKT ? (T_) + 2 : NKT - 1);                          \
    __builtin_amdgcn_s_setprio(1);                                           \
    mfmaCl(af, BLc, BHc);                                                    \
    __builtin_amdgcn_s_setprio(0);                                           \
    loadB((T_) + 1 < NKT ? (T_) + 1 : NKT - 1, BLn, BHn);                    \
    asm volatile("s_waitcnt lgkmcnt(0)" ::: "memory");                       \
    asm volatile("s_waitcnt vmcnt(6)" ::: "memory");                         \
    __builtin_amdgcn_s_barrier();                                            \
    buf = (buf == 2) ? 0 : buf + 1;                                          \
  }

#pragma unroll 1
  for (int t2 = 0; t2 < NKT; t2 += 2) {
    GEMM_BODY(t2,     blA, bhA, blB, bhB);
    GEMM_BODY(t2 + 1, blB, bhB, blA, bhA);
  }
#undef GEMM_BODY

  // ---- epilogue: store-once ----
  int cols[2]; float bLo[2], bHi[2];
#pragma unroll
  for (int fc = 0; fc < 2; ++fc) {
    cols[fc] = colTile * BN + wn * 32 + fc * 16 + (lane & 15);
    bLo[fc] = bias[lo * ODIM + cols[fc]];
    bHi[fc] = bias[hi * ODIM + cols[fc]];
  }
#pragma unroll
  for (int fr = 0; fr < 8; ++fr) {
#pragma unroll
    for (int rr = 0; rr < 4; ++rr) {
      const int row = wm * 128 + fr * 16 + (lane >> 4) * 4 + rr;
      if (row < ce) {
        const int tok = tokL[row];
        const float2 ww = wgtL[row];
        float* orow = out + (size_t)tok * ODIM;
#pragma unroll
        for (int fc = 0; fc < 2; ++fc)
          orow[cols[fc]] = ww.x * (acc[0][fr][fc][rr] + bLo[fc]) +
                           ww.y * (acc[1][fr][fc][rr] + bHi[fc]);
      }
    }
  }
}

// ---------------- emergency fallback (ws too small): slow but correct ----------------
__global__ __launch_bounds__(256) void naive_moe(
    const float* __restrict__ x, const float* __restrict__ gate,
    const float* __restrict__ ew, const float* __restrict__ eb,
    float* __restrict__ out, int T)
{
  const int tok = blockIdx.x, tid = threadIdx.x;
  __shared__ float xs[LDIM];
  __shared__ float logits[E_EXP];
  __shared__ float sw1, sw2; __shared__ int si1, si2;
  for (int i = tid; i < LDIM; i += 256) xs[i] = x[(size_t)tok * LDIM + i];
  __syncthreads();
  const int wid = tid >> 6, lane = tid & 63;
  for (int e = wid; e < E_EXP; e += 4) {
    float a = 0.f;
    for (int i = lane; i < LDIM; i += 64) a += xs[i] * gate[e * LDIM + i];
    for (int off = 32; off >= 1; off >>= 1) a += __shfl_xor(a, off, 64);
    if (lane == 0) logits[e] = a;
  }
  __syncthreads();
  if (tid == 0) {
    int i1 = 0; float m1 = logits[0];
    for (int e = 1; e < E_EXP; ++e) if (logits[e] > m1) { m1 = logits[e]; i1 = e; }
    int i2 = -1; float m2 = -1e30f;
    for (int e = 0; e < E_EXP; ++e) if (e != i1 && logits[e] > m2) { m2 = logits[e]; i2 = e; }
    float s = 0.f;
    for (int e = 0; e < E_EXP; ++e) s += __expf(logits[e] - m1);
    si1 = i1; si2 = i2; sw1 = 1.f / s; sw2 = __expf(m2 - m1) / s;
  }
  __syncthreads();
  const int i1 = si1, i2 = si2; const float w1 = sw1, w2 = sw2;
  for (int o = tid; o < ODIM; o += 256) {
    float a1 = 0.f, a2 = 0.f;
    const float* p1 = ew + ((size_t)i1 * ODIM + o) * LDIM;
    const float* p2 = ew + ((size_t)i2 * ODIM + o) * LDIM;
    for (int l = 0; l < LDIM; ++l) { a1 += xs[l] * p1[l]; a2 += xs[l] * p2[l]; }
    out[(size_t)tok * ODIM + o] =
        w1 * (a1 + eb[i1 * ODIM + o]) + w2 * (a2 + eb[i2 * ODIM + o]);
  }
}

extern "C" void kernel_launch(void* const* d_in, const int* in_sizes, int n_in,
                              void* d_out, int out_size, void* d_ws, size_t ws_size,
                              hipStream_t stream) {
  const float* x    = (const float*)d_in[0];
  const float* gate = (const float*)d_in[1];
  const float* ew   = (const float*)d_in[2];
  const float* eb   = (const float*)d_in[3];
  float* out = (float*)d_out;
  const int T = in_sizes[0] / LDIM;  // 32768
  const int NB = (T + 2047) / 2048; // 16

  // ws layout (aligned regions)
  const size_t offSel   = 0;                                   // T ints
  const size_t offPw    = offSel + (size_t)T * 4;              // T float2
  const size_t offHist  = offPw + (size_t)T * 8;               // NB*64 ints
  const size_t offBBase = offHist + (size_t)NB * NPAIR * 4;    // NB*64 ints
  const size_t offDesc  = offBBase + (size_t)NB * NPAIR * 4;   // MAXRT int4
  const size_t offMeta  = offDesc + (size_t)MAXRT * 16;        // 1 int (pad 256)
  const size_t offTokC  = offMeta + 256;                       // T ints
  const size_t offWC    = offTokC + (size_t)T * 4;             // T float2
  const size_t offXb    = offWC + (size_t)T * 8;               // T*L bf16 = 64MB
  const size_t offWb    = offXb + (size_t)T * LDIM * 2;        // 16MB
  const size_t need     = offWb + (size_t)E_EXP * ODIM * LDIM * 2;  // ~81MB

  if (ws_size < need) {
    naive_moe<<<T, 256, 0, stream>>>(x, gate, ew, eb, out, T);
    return;
  }

  char* ws = (char*)d_ws;

  route_kernel<<<(T + 15) / 16, 256, 0, stream>>>(
      x, gate, (unsigned short*)(ws + offXb), (int*)(ws + offSel),
      (float2*)(ws + offPw), T);

  const int n4 = E_EXP * ODIM * LDIM / 4;
  convw_kernel<<<(n4 + 255) / 256, 256, 0, stream>>>(ew, (unsigned short*)(ws + offWb), n4);

  hist_kernel<<<NB, 256, 0, stream>>>(
      (const int*)(ws + offSel), (int*)(ws + offHist), T);

  finalize_kernel<<<1, 64, 0, stream>>>(
      (const int*)(ws + offHist), NB, (int*)(ws + offBBase),
      (int4*)(ws + offDesc), (int*)(ws + offMeta));

  scatter_kernel<<<NB, 256, 0, stream>>>(
      (const int*)(ws + offSel), (const float2*)(ws + offPw),
      (const int*)(ws + offBBase), (int*)(ws + offTokC),
      (float2*)(ws + offWC), T);

  moe_gemm_pair<<<GEMM_GRID, 512, 0, stream>>>(
      (const unsigned short*)(ws + offXb), (const unsigned short*)(ws + offWb),
      eb, (const int4*)(ws + offDesc), (const int*)(ws + offMeta),
      (const int*)(ws + offTokC), (const float2*)(ws + offWC), out);
}

// Round 13
// 266.435 us; speedup vs baseline: 1.3079x; 1.3079x over previous
//
#include <hip/hip_runtime.h>
#include <cstdint>
#include <cstddef>

#define E_EXP 8
#define LDIM 1024
#define ODIM 1024
#define NPAIR 64            // key = lo*8+hi, lo<hi (<=28 nonempty)

// ---- pair-grouped GEMM geometry: 256x128 tile, K=1024 over TWO experts ----
#define BM 256
#define BN 128
#define BK 32
#define NKT (LDIM / BK)     // 32 K-tiles
#define MAXRT 160           // sum ceil(cnt/256) <= 32768/256 + 28 = 156
#define GEMM_GRID (MAXRT * 8)  // 1280 = 8 * 160 (8 col tiles)
#define CPX (GEMM_GRID / 8)    // 160 per XCD chunk

typedef __bf16 bf16x8 __attribute__((ext_vector_type(8)));
typedef float f32x4 __attribute__((ext_vector_type(4)));

__device__ __forceinline__ unsigned short f2bf(float f) {
  uint32_t u = __float_as_uint(f);
  u += 0x7FFFu + ((u >> 16) & 1u);   // round-to-nearest-even
  return (unsigned short)(u >> 16);
}

__device__ __forceinline__ void gload_lds16(const void* g, void* l) {
  __builtin_amdgcn_global_load_lds(
      (const __attribute__((address_space(1))) unsigned int*)g,
      (__attribute__((address_space(3))) unsigned int*)l, 16, 0, 0);
}

// ---------------- routing + x->bf16 conversion: 4 tokens per wave ----------------
__global__ __launch_bounds__(256) void route_kernel(
    const float* __restrict__ x, const float* __restrict__ gate,
    unsigned short* __restrict__ xb, int* __restrict__ sel,
    float2* __restrict__ pw, int T)
{
  const int wid = threadIdx.x >> 6, lane = threadIdx.x & 63;
  const int tokBase = blockIdx.x * 16 + wid * 4;
  if (tokBase >= T) return;
  const float* xr = x + (size_t)tokBase * LDIM;
  unsigned short* xbr = xb + (size_t)tokBase * LDIM;

  float acc[4][E_EXP];
#pragma unroll
  for (int j = 0; j < 4; ++j)
#pragma unroll
    for (int e = 0; e < E_EXP; ++e) acc[j][e] = 0.f;

#pragma unroll
  for (int it = 0; it < 4; ++it) {
    const int c = it * 256 + lane * 4;
    float4 xv[4];
#pragma unroll
    for (int j = 0; j < 4; ++j) {
      xv[j] = *(const float4*)(xr + (size_t)j * LDIM + c);
      ushort4 bv;
      bv.x = f2bf(xv[j].x); bv.y = f2bf(xv[j].y);
      bv.z = f2bf(xv[j].z); bv.w = f2bf(xv[j].w);
      *(ushort4*)(xbr + (size_t)j * LDIM + c) = bv;
    }
#pragma unroll
    for (int e = 0; e < E_EXP; ++e) {
      float4 gv = *(const float4*)(gate + e * LDIM + c);
#pragma unroll
      for (int j = 0; j < 4; ++j)
        acc[j][e] += xv[j].x * gv.x + xv[j].y * gv.y + xv[j].z * gv.z + xv[j].w * gv.w;
    }
  }
#pragma unroll
  for (int off = 32; off >= 1; off >>= 1) {
#pragma unroll
    for (int j = 0; j < 4; ++j)
#pragma unroll
      for (int e = 0; e < E_EXP; ++e) acc[j][e] += __shfl_xor(acc[j][e], off, 64);
  }
  if (lane < 4) {
    const int tok = tokBase + lane;
    if (tok < T) {
      float lg[E_EXP];
#pragma unroll
      for (int e = 0; e < E_EXP; ++e) lg[e] = acc[lane][e];
      int i1 = 0; float m1 = lg[0];
#pragma unroll
      for (int e = 1; e < E_EXP; ++e) if (lg[e] > m1) { m1 = lg[e]; i1 = e; }
      int i2 = -1; float m2 = -1e30f;
#pragma unroll
      for (int e = 0; e < E_EXP; ++e) if (e != i1 && lg[e] > m2) { m2 = lg[e]; i2 = e; }
      float s = 0.f;
#pragma unroll
      for (int e = 0; e < E_EXP; ++e) s += __expf(lg[e] - m1);
      const float inv = 1.f / s;
      sel[tok] = i1 | (i2 << 4);
      pw[tok] = make_float2(inv, __expf(m2 - m1) * inv);
    }
  }
}

// ---------------- per-block pair histogram (NO global atomics) ----------------
__global__ __launch_bounds__(256) void hist_kernel(
    const int* __restrict__ sel, int* __restrict__ hist2d, int T)
{
  __shared__ int h[NPAIR];
  const int tid = threadIdx.x;
  if (tid < NPAIR) h[tid] = 0;
  __syncthreads();
  const int t0 = blockIdx.x * 2048;
#pragma unroll
  for (int i = 0; i < 8; ++i) {
    const int t = t0 + i * 256 + tid;
    if (t < T) {
      const int s = sel[t];
      const int i1 = s & 15, i2 = (s >> 4) & 15;
      const int lo = i1 < i2 ? i1 : i2, hi = i1 < i2 ? i2 : i1;
      atomicAdd(&h[lo * 8 + hi], 1);
    }
  }
  __syncthreads();
  if (tid < NPAIR) hist2d[blockIdx.x * NPAIR + tid] = h[tid];
}

// ---------------- prefix sums + row-tile descriptors (parallel over pairs) ----
__global__ void finalize_kernel(
    const int* __restrict__ hist2d, int nb,
    int* __restrict__ blockBase, int4* __restrict__ desc, int* __restrict__ meta)
{
  __shared__ int pcnt[NPAIR], pbase[NPAIR];
  const int p = threadIdx.x;
  if (p < NPAIR) {
    int c = 0;
#pragma unroll 4
    for (int b = 0; b < nb; ++b) c += hist2d[b * NPAIR + p];
    pcnt[p] = c;
  }
  __syncthreads();
  if (p == 0) {
    int s = 0;
    for (int q = 0; q < NPAIR; ++q) { pbase[q] = s; s += pcnt[q]; }
  }
  __syncthreads();
  if (p < NPAIR) {
    int run = pbase[p];
    for (int b = 0; b < nb; ++b) {
      blockBase[b * NPAIR + p] = run;
      run += hist2d[b * NPAIR + p];
    }
  }
  if (p == 0) {
    int rt = 0;
    for (int q = 0; q < NPAIR; ++q) {
      const int lo = q >> 3, hi = q & 7;
      for (int j = 0; j * BM < pcnt[q]; ++j) {
        int rows = pcnt[q] - j * BM; if (rows > BM) rows = BM;
        desc[rt] = make_int4(lo | (hi << 8), pbase[q] + j * BM, rows, 0);
        ++rt;
      }
    }
    meta[0] = rt;
  }
}

// ---------------- deterministic scatter into compact pair lists ----------------
__global__ __launch_bounds__(256) void scatter_kernel(
    const int* __restrict__ sel, const float2* __restrict__ pw,
    const int* __restrict__ blockBase, int* __restrict__ tokC,
    float2* __restrict__ wC, int T)
{
  __shared__ int cur[NPAIR];
  const int tid = threadIdx.x;
  if (tid < NPAIR) cur[tid] = blockBase[blockIdx.x * NPAIR + tid];
  __syncthreads();
  const int t0 = blockIdx.x * 2048;
#pragma unroll
  for (int i = 0; i < 8; ++i) {
    const int t = t0 + i * 256 + tid;
    if (t < T) {
      const int s = sel[t];
      const int i1 = s & 15, i2 = (s >> 4) & 15;
      const float2 w = pw[t];
      const int lo = i1 < i2 ? i1 : i2, hi = i1 < i2 ? i2 : i1;
      const float wlo = i1 < i2 ? w.x : w.y;
      const float whi = i1 < i2 ? w.y : w.x;
      const int pos = atomicAdd(&cur[lo * 8 + hi], 1);   // LDS atomic only
      tokC[pos] = t;
      wC[pos] = make_float2(wlo, whi);
    }
  }
}

// ---------------- expert_w -> bf16 (row-major) ----------------
__global__ __launch_bounds__(256) void convw_kernel(
    const float* __restrict__ w, unsigned short* __restrict__ wb, int n4)
{
  int i = blockIdx.x * 256 + threadIdx.x;
  if (i >= n4) return;
  float4 v = *(const float4*)(w + (size_t)i * 4);
  ushort4 b;
  b.x = f2bf(v.x); b.y = f2bf(v.y); b.z = f2bf(v.z); b.w = f2bf(v.w);
  *(ushort4*)(wb + (size_t)i * 4) = b;
}

// ---------------- pair-grouped gathered GEMM: 256x128, two experts, store-once ----
// R8 champion body (verbatim): 3-deep LDS ring (96KB), ONE barrier per body, NO
// explicit LDS drain before MFMA (compiler inserts fine-grained lgkmcnt waits so
// the LDS drain hides under the MFMA cluster).
// body t = { ds_read frags(buf) x12 | stage(tile t+2 -> buffer freed at t-1) |
//            setprio(1) MFMA x32 setprio(0) | lgkm(0) | vmcnt(4) | barrier }.
// vmcnt(4) leaves stage(t+2) in flight and certifies stage(t+1), issued a full
// body (~3000 cyc) earlier.
__global__ __launch_bounds__(512, 2) void moe_gemm_pair(
    const unsigned short* __restrict__ xb, const unsigned short* __restrict__ wb,
    const float* __restrict__ bias, const int4* __restrict__ desc,
    const int* __restrict__ meta, const int* __restrict__ tokC,
    const float2* __restrict__ wC, float* __restrict__ out)
{
  __shared__ __align__(16) unsigned short ldsA[3][BM * BK];       // 3 x 16KB
  __shared__ __align__(16) unsigned short ldsB[3][2 * BN * BK];   // 3 x 16KB
  const int tid = threadIdx.x;
  const int lane = tid & 63, w = tid >> 6;
  const int wm = w >> 2, wn = w & 3;   // 2(M) x 4(N); per-wave out 128 x 32 per expert

  const int totalRT = meta[0];
  const int swz = ((int)blockIdx.x & 7) * CPX + ((int)blockIdx.x >> 3);
  if (swz >= totalRT * 8) return;
  const int rt = swz >> 3, colTile = swz & 7;
  const int4 d = desc[rt];
  const int lo = d.x & 255, hi = d.x >> 8;
  const int start = d.y, ce = d.z;
  const int* tokL = tokC + start;
  const float2* wgtL = wC + start;

  // ---- staging sources ----
  const int s = lane & 3;
  const int rA0 = w * 32 + (lane >> 2);
  const int rA1 = rA0 + 16;
  const int gA0 = s ^ ((rA0 >> 1) & 3);
  const int gA1 = s ^ ((rA1 >> 1) & 3);
  const int tA0 = tokL[rA0 < ce ? rA0 : ce - 1];
  const int tA1 = tokL[rA1 < ce ? rA1 : ce - 1];
  const char* aSrc0 = (const char*)(xb + (size_t)tA0 * LDIM) + gA0 * 16;
  const char* aSrc1 = (const char*)(xb + (size_t)tA1 * LDIM) + gA1 * 16;
  const int rB = w * 16 + (lane >> 2);           // 0..127
  const int gB = s ^ ((rB >> 1) & 3);
  const int colB = colTile * BN + rB;
  const char* bSrcLo = (const char*)(wb + ((size_t)lo * ODIM + colB) * LDIM) + gB * 16;
  const char* bSrcHi = (const char*)(wb + ((size_t)hi * ODIM + colB) * LDIM) + gB * 16;

  // ---- ds_read offsets (shorts) ----
  int offA[8], offB[2];
#pragma unroll
  for (int fr = 0; fr < 8; ++fr) {
    const int r = wm * 128 + fr * 16 + (lane & 15);
    offA[fr] = r * BK + (((lane >> 4) ^ ((r >> 1) & 3)) * 8);
  }
#pragma unroll
  for (int fc = 0; fc < 2; ++fc) {
    const int r = wn * 32 + fc * 16 + (lane & 15);
    offB[fc] = r * BK + (((lane >> 4) ^ ((r >> 1) & 3)) * 8);
  }

  auto stage = [&](int b, int kt) {
    const int kb = kt * 64;  // bytes
    gload_lds16(aSrc0 + kb, &ldsA[b][w * 1024]);
    gload_lds16(aSrc1 + kb, &ldsA[b][w * 1024 + 512]);
    gload_lds16(bSrcLo + kb, &ldsB[b][w * 512]);
    gload_lds16(bSrcHi + kb, &ldsB[b][4096 + w * 512]);
  };

  f32x4 acc[2][8][2] = {};

  // ---- prologue: stage tiles 0,1 into bufs 0,1; certify tile 0 ----
  stage(0, 0); stage(1, 1);
  asm volatile("s_waitcnt vmcnt(4)" ::: "memory");   // stage 0 complete
  __builtin_amdgcn_s_barrier();

  int buf = 0;
#pragma unroll 1
  for (int kt = 0; kt < NKT; ++kt) {
    const unsigned short* As = &ldsA[buf][0];
    const unsigned short* Bs = &ldsB[buf][0];
    bf16x8 af[8], bl0, bl1, bh0, bh1;
#pragma unroll
    for (int fr = 0; fr < 8; ++fr) af[fr] = *(const bf16x8*)(As + offA[fr]);
    bl0 = *(const bf16x8*)(Bs + offB[0]);
    bl1 = *(const bf16x8*)(Bs + offB[1]);
    bh0 = *(const bf16x8*)(Bs + 4096 + offB[0]);
    bh1 = *(const bf16x8*)(Bs + 4096 + offB[1]);

    // stage tile kt+2 into the buffer read at body kt-1 (reads published there)
    int sb = buf + 2; if (sb > 2) sb -= 3;
    stage(sb, kt + 2 < NKT ? kt + 2 : NKT - 1);

    __builtin_amdgcn_s_setprio(1);
#pragma unroll
    for (int fr = 0; fr < 8; ++fr) {
      acc[0][fr][0] = __builtin_amdgcn_mfma_f32_16x16x32_bf16(af[fr], bl0, acc[0][fr][0], 0, 0, 0);
      acc[0][fr][1] = __builtin_amdgcn_mfma_f32_16x16x32_bf16(af[fr], bl1, acc[0][fr][1], 0, 0, 0);
      acc[1][fr][0] = __builtin_amdgcn_mfma_f32_16x16x32_bf16(af[fr], bh0, acc[1][fr][0], 0, 0, 0);
      acc[1][fr][1] = __builtin_amdgcn_mfma_f32_16x16x32_bf16(af[fr], bh1, acc[1][fr][1], 0, 0, 0);
    }
    __builtin_amdgcn_s_setprio(0);

    asm volatile("s_waitcnt lgkmcnt(0)" ::: "memory");  // all my reads of buf done
    asm volatile("s_waitcnt vmcnt(4)" ::: "memory");    // stage(kt+1) complete
    __builtin_amdgcn_s_barrier();                       // publish both
    buf = (buf == 2) ? 0 : buf + 1;
  }

  // ---- epilogue: store-once ----
  int cols[2]; float bLo[2], bHi[2];
#pragma unroll
  for (int fc = 0; fc < 2; ++fc) {
    cols[fc] = colTile * BN + wn * 32 + fc * 16 + (lane & 15);
    bLo[fc] = bias[lo * ODIM + cols[fc]];
    bHi[fc] = bias[hi * ODIM + cols[fc]];
  }
#pragma unroll
  for (int fr = 0; fr < 8; ++fr) {
#pragma unroll
    for (int rr = 0; rr < 4; ++rr) {
      const int row = wm * 128 + fr * 16 + (lane >> 4) * 4 + rr;
      if (row < ce) {
        const int tok = tokL[row];
        const float2 ww = wgtL[row];
        float* orow = out + (size_t)tok * ODIM;
#pragma unroll
        for (int fc = 0; fc < 2; ++fc)
          orow[cols[fc]] = ww.x * (acc[0][fr][fc][rr] + bLo[fc]) +
                           ww.y * (acc[1][fr][fc][rr] + bHi[fc]);
      }
    }
  }
}

// ---------------- emergency fallback (ws too small): slow but correct ----------------
__global__ __launch_bounds__(256) void naive_moe(
    const float* __restrict__ x, const float* __restrict__ gate,
    const float* __restrict__ ew, const float* __restrict__ eb,
    float* __restrict__ out, int T)
{
  const int tok = blockIdx.x, tid = threadIdx.x;
  __shared__ float xs[LDIM];
  __shared__ float logits[E_EXP];
  __shared__ float sw1, sw2; __shared__ int si1, si2;
  for (int i = tid; i < LDIM; i += 256) xs[i] = x[(size_t)tok * LDIM + i];
  __syncthreads();
  const int wid = tid >> 6, lane = tid & 63;
  for (int e = wid; e < E_EXP; e += 4) {
    float a = 0.f;
    for (int i = lane; i < LDIM; i += 64) a += xs[i] * gate[e * LDIM + i];
    for (int off = 32; off >= 1; off >>= 1) a += __shfl_xor(a, off, 64);
    if (lane == 0) logits[e] = a;
  }
  __syncthreads();
  if (tid == 0) {
    int i1 = 0; float m1 = logits[0];
    for (int e = 1; e < E_EXP; ++e) if (logits[e] > m1) { m1 = logits[e]; i1 = e; }
    int i2 = -1; float m2 = -1e30f;
    for (int e = 0; e < E_EXP; ++e) if (e != i1 && logits[e] > m2) { m2 = logits[e]; i2 = e; }
    float s = 0.f;
    for (int e = 0; e < E_EXP; ++e) s += __expf(logits[e] - m1);
    si1 = i1; si2 = i2; sw1 = 1.f / s; sw2 = __expf(m2 - m1) / s;
  }
  __syncthreads();
  const int i1 = si1, i2 = si2; const float w1 = sw1, w2 = sw2;
  for (int o = tid; o < ODIM; o += 256) {
    float a1 = 0.f, a2 = 0.f;
    const float* p1 = ew + ((size_t)i1 * ODIM + o) * LDIM;
    const float* p2 = ew + ((size_t)i2 * ODIM + o) * LDIM;
    for (int l = 0; l < LDIM; ++l) { a1 += xs[l] * p1[l]; a2 += xs[l] * p2[l]; }
    out[(size_t)tok * ODIM + o] =
        w1 * (a1 + eb[i1 * ODIM + o]) + w2 * (a2 + eb[i2 * ODIM + o]);
  }
}

extern "C" void kernel_launch(void* const* d_in, const int* in_sizes, int n_in,
                              void* d_out, int out_size, void* d_ws, size_t ws_size,
                              hipStream_t stream) {
  const float* x    = (const float*)d_in[0];
  const float* gate = (const float*)d_in[1];
  const float* ew   = (const float*)d_in[2];
  const float* eb   = (const float*)d_in[3];
  float* out = (float*)d_out;
  const int T = in_sizes[0] / LDIM;  // 32768
  const int NB = (T + 2047) / 2048; // 16

  // ws layout (aligned regions)
  const size_t offSel   = 0;                                   // T ints
  const size_t offPw    = offSel + (size_t)T * 4;              // T float2
  const size_t offHist  = offPw + (size_t)T * 8;               // NB*64 ints
  const size_t offBBase = offHist + (size_t)NB * NPAIR * 4;    // NB*64 ints
  const size_t offDesc  = offBBase + (size_t)NB * NPAIR * 4;   // MAXRT int4
  const size_t offMeta  = offDesc + (size_t)MAXRT * 16;        // 1 int (pad 256)
  const size_t offTokC  = offMeta + 256;                       // T ints
  const size_t offWC    = offTokC + (size_t)T * 4;             // T float2
  const size_t offXb    = offWC + (size_t)T * 8;               // T*L bf16 = 64MB
  const size_t offWb    = offXb + (size_t)T * LDIM * 2;        // 16MB
  const size_t need     = offWb + (size_t)E_EXP * ODIM * LDIM * 2;  // ~81MB

  if (ws_size < need) {
    naive_moe<<<T, 256, 0, stream>>>(x, gate, ew, eb, out, T);
    return;
  }

  char* ws = (char*)d_ws;

  route_kernel<<<(T + 15) / 16, 256, 0, stream>>>(
      x, gate, (unsigned short*)(ws + offXb), (int*)(ws + offSel),
      (float2*)(ws + offPw), T);

  const int n4 = E_EXP * ODIM * LDIM / 4;
  convw_kernel<<<(n4 + 255) / 256, 256, 0, stream>>>(ew, (unsigned short*)(ws + offWb), n4);

  hist_kernel<<<NB, 256, 0, stream>>>(
      (const int*)(ws + offSel), (int*)(ws + offHist), T);

  finalize_kernel<<<1, 64, 0, stream>>>(
      (const int*)(ws + offHist), NB, (int*)(ws + offBBase),
      (int4*)(ws + offDesc), (int*)(ws + offMeta));

  scatter_kernel<<<NB, 256, 0, stream>>>(
      (const int*)(ws + offSel), (const float2*)(ws + offPw),
      (const int*)(ws + offBBase), (int*)(ws + offTokC),
      (float2*)(ws + offWC), T);

  moe_gemm_pair<<<GEMM_GRID, 512, 0, stream>>>(
      (const unsigned short*)(ws + offXb), (const unsigned short*)(ws + offWb),
      eb, (const int4*)(ws + offDesc), (const int*)(ws + offMeta),
      (const int*)(ws + offTokC), (const float2*)(ws + offWC), out);
}

// Round 14
// 266.150 us; speedup vs baseline: 1.3093x; 1.0011x over previous
//
#include <hip/hip_runtime.h>
#include <cstdint>
#include <cstddef>

#define E_EXP 8
#define LDIM 1024
#define ODIM 1024
#define NPAIR 64            // key = lo*8+hi, lo<hi (<=28 nonempty)

// ---- pair-grouped GEMM geometry: 256x128 tile, K=1024 over TWO experts ----
#define BM 256
#define BN 128
#define BK 32
#define NKT (LDIM / BK)     // 32 K-tiles
#define MAXRT 160           // sum ceil(cnt/256) <= 32768/256 + 28 = 156
#define GEMM_GRID (MAXRT * 8)  // 1280 = 8 * 160 (8 col tiles)
#define CPX (GEMM_GRID / 8)    // 160 per XCD chunk

#define CONV_BLOCKS 8192    // (E*O*L/4) / 256 = 2097152/256, exact

typedef __bf16 bf16x8 __attribute__((ext_vector_type(8)));
typedef float f32x4 __attribute__((ext_vector_type(4)));

__device__ __forceinline__ unsigned short f2bf(float f) {
  uint32_t u = __float_as_uint(f);
  u += 0x7FFFu + ((u >> 16) & 1u);   // round-to-nearest-even
  return (unsigned short)(u >> 16);
}

__device__ __forceinline__ void gload_lds16(const void* g, void* l) {
  __builtin_amdgcn_global_load_lds(
      (const __attribute__((address_space(1))) unsigned int*)g,
      (__attribute__((address_space(3))) unsigned int*)l, 16, 0, 0);
}

// ------- FUSED: expert_w->bf16 conversion + routing + x->bf16 (4 tok/wave) -------
// Blocks [0, CONV_BLOCKS) convert ew (independent work, rides in route's BW
// shadow); blocks [CONV_BLOCKS, +2048) are the R13 route kernel unchanged.
__global__ __launch_bounds__(256) void route_conv_kernel(
    const float* __restrict__ x, const float* __restrict__ gate,
    const float* __restrict__ ew, unsigned short* __restrict__ xb,
    unsigned short* __restrict__ wb, int* __restrict__ sel,
    float2* __restrict__ pw, int T)
{
  const int bid = blockIdx.x;
  if (bid < CONV_BLOCKS) {
    const int i = bid * 256 + threadIdx.x;   // < E*O*L/4 by construction
    float4 v = *(const float4*)(ew + (size_t)i * 4);
    ushort4 b;
    b.x = f2bf(v.x); b.y = f2bf(v.y); b.z = f2bf(v.z); b.w = f2bf(v.w);
    *(ushort4*)(wb + (size_t)i * 4) = b;
    return;
  }
  const int rb = bid - CONV_BLOCKS;
  const int wid = threadIdx.x >> 6, lane = threadIdx.x & 63;
  const int tokBase = rb * 16 + wid * 4;
  if (tokBase >= T) return;
  const float* xr = x + (size_t)tokBase * LDIM;
  unsigned short* xbr = xb + (size_t)tokBase * LDIM;

  float acc[4][E_EXP];
#pragma unroll
  for (int j = 0; j < 4; ++j)
#pragma unroll
    for (int e = 0; e < E_EXP; ++e) acc[j][e] = 0.f;

#pragma unroll
  for (int it = 0; it < 4; ++it) {
    const int c = it * 256 + lane * 4;
    float4 xv[4];
#pragma unroll
    for (int j = 0; j < 4; ++j) {
      xv[j] = *(const float4*)(xr + (size_t)j * LDIM + c);
      ushort4 bv;
      bv.x = f2bf(xv[j].x); bv.y = f2bf(xv[j].y);
      bv.z = f2bf(xv[j].z); bv.w = f2bf(xv[j].w);
      *(ushort4*)(xbr + (size_t)j * LDIM + c) = bv;
    }
#pragma unroll
    for (int e = 0; e < E_EXP; ++e) {
      float4 gv = *(const float4*)(gate + e * LDIM + c);
#pragma unroll
      for (int j = 0; j < 4; ++j)
        acc[j][e] += xv[j].x * gv.x + xv[j].y * gv.y + xv[j].z * gv.z + xv[j].w * gv.w;
    }
  }
#pragma unroll
  for (int off = 32; off >= 1; off >>= 1) {
#pragma unroll
    for (int j = 0; j < 4; ++j)
#pragma unroll
      for (int e = 0; e < E_EXP; ++e) acc[j][e] += __shfl_xor(acc[j][e], off, 64);
  }
  if (lane < 4) {
    const int tok = tokBase + lane;
    if (tok < T) {
      float lg[E_EXP];
#pragma unroll
      for (int e = 0; e < E_EXP; ++e) lg[e] = acc[lane][e];
      int i1 = 0; float m1 = lg[0];
#pragma unroll
      for (int e = 1; e < E_EXP; ++e) if (lg[e] > m1) { m1 = lg[e]; i1 = e; }
      int i2 = -1; float m2 = -1e30f;
#pragma unroll
      for (int e = 0; e < E_EXP; ++e) if (e != i1 && lg[e] > m2) { m2 = lg[e]; i2 = e; }
      float s = 0.f;
#pragma unroll
      for (int e = 0; e < E_EXP; ++e) s += __expf(lg[e] - m1);
      const float inv = 1.f / s;
      sel[tok] = i1 | (i2 << 4);
      pw[tok] = make_float2(inv, __expf(m2 - m1) * inv);
    }
  }
}

// ---------------- per-block pair histogram (NO global atomics) ----------------
__global__ __launch_bounds__(256) void hist_kernel(
    const int* __restrict__ sel, int* __restrict__ hist2d, int T)
{
  __shared__ int h[NPAIR];
  const int tid = threadIdx.x;
  if (tid < NPAIR) h[tid] = 0;
  __syncthreads();
  const int t0 = blockIdx.x * 2048;
#pragma unroll
  for (int i = 0; i < 8; ++i) {
    const int t = t0 + i * 256 + tid;
    if (t < T) {
      const int s = sel[t];
      const int i1 = s & 15, i2 = (s >> 4) & 15;
      const int lo = i1 < i2 ? i1 : i2, hi = i1 < i2 ? i2 : i1;
      atomicAdd(&h[lo * 8 + hi], 1);
    }
  }
  __syncthreads();
  if (tid < NPAIR) hist2d[blockIdx.x * NPAIR + tid] = h[tid];
}

// ---------------- prefix sums + row-tile descriptors (parallel over pairs) ----
__global__ void finalize_kernel(
    const int* __restrict__ hist2d, int nb,
    int* __restrict__ blockBase, int4* __restrict__ desc, int* __restrict__ meta)
{
  __shared__ int pcnt[NPAIR], pbase[NPAIR];
  const int p = threadIdx.x;
  if (p < NPAIR) {
    int c = 0;
#pragma unroll 4
    for (int b = 0; b < nb; ++b) c += hist2d[b * NPAIR + p];
    pcnt[p] = c;
  }
  __syncthreads();
  if (p == 0) {
    int s = 0;
    for (int q = 0; q < NPAIR; ++q) { pbase[q] = s; s += pcnt[q]; }
  }
  __syncthreads();
  if (p < NPAIR) {
    int run = pbase[p];
    for (int b = 0; b < nb; ++b) {
      blockBase[b * NPAIR + p] = run;
      run += hist2d[b * NPAIR + p];
    }
  }
  if (p == 0) {
    int rt = 0;
    for (int q = 0; q < NPAIR; ++q) {
      const int lo = q >> 3, hi = q & 7;
      for (int j = 0; j * BM < pcnt[q]; ++j) {
        int rows = pcnt[q] - j * BM; if (rows > BM) rows = BM;
        desc[rt] = make_int4(lo | (hi << 8), pbase[q] + j * BM, rows, 0);
        ++rt;
      }
    }
    meta[0] = rt;
  }
}

// ---------------- deterministic scatter into compact pair lists ----------------
__global__ __launch_bounds__(256) void scatter_kernel(
    const int* __restrict__ sel, const float2* __restrict__ pw,
    const int* __restrict__ blockBase, int* __restrict__ tokC,
    float2* __restrict__ wC, int T)
{
  __shared__ int cur[NPAIR];
  const int tid = threadIdx.x;
  if (tid < NPAIR) cur[tid] = blockBase[blockIdx.x * NPAIR + tid];
  __syncthreads();
  const int t0 = blockIdx.x * 2048;
#pragma unroll
  for (int i = 0; i < 8; ++i) {
    const int t = t0 + i * 256 + tid;
    if (t < T) {
      const int s = sel[t];
      const int i1 = s & 15, i2 = (s >> 4) & 15;
      const float2 w = pw[t];
      const int lo = i1 < i2 ? i1 : i2, hi = i1 < i2 ? i2 : i1;
      const float wlo = i1 < i2 ? w.x : w.y;
      const float whi = i1 < i2 ? w.y : w.x;
      const int pos = atomicAdd(&cur[lo * 8 + hi], 1);   // LDS atomic only
      tokC[pos] = t;
      wC[pos] = make_float2(wlo, whi);
    }
  }
}

// ---------------- pair-grouped gathered GEMM: 256x128, two experts, store-once ----
// R8 champion body (verbatim): 3-deep LDS ring (96KB), ONE barrier per body, NO
// explicit LDS drain before MFMA (compiler inserts fine-grained lgkmcnt waits so
// the LDS drain hides under the MFMA cluster).
// body t = { ds_read frags(buf) x12 | stage(tile t+2 -> buffer freed at t-1) |
//            setprio(1) MFMA x32 setprio(0) | lgkm(0) | vmcnt(4) | barrier }.
// vmcnt(4) leaves stage(t+2) in flight and certifies stage(t+1), issued a full
// body (~3000 cyc) earlier.
__global__ __launch_bounds__(512, 2) void moe_gemm_pair(
    const unsigned short* __restrict__ xb, const unsigned short* __restrict__ wb,
    const float* __restrict__ bias, const int4* __restrict__ desc,
    const int* __restrict__ meta, const int* __restrict__ tokC,
    const float2* __restrict__ wC, float* __restrict__ out)
{
  __shared__ __align__(16) unsigned short ldsA[3][BM * BK];       // 3 x 16KB
  __shared__ __align__(16) unsigned short ldsB[3][2 * BN * BK];   // 3 x 16KB
  const int tid = threadIdx.x;
  const int lane = tid & 63, w = tid >> 6;
  const int wm = w >> 2, wn = w & 3;   // 2(M) x 4(N); per-wave out 128 x 32 per expert

  const int totalRT = meta[0];
  const int swz = ((int)blockIdx.x & 7) * CPX + ((int)blockIdx.x >> 3);
  if (swz >= totalRT * 8) return;
  const int rt = swz >> 3, colTile = swz & 7;
  const int4 d = desc[rt];
  const int lo = d.x & 255, hi = d.x >> 8;
  const int start = d.y, ce = d.z;
  const int* tokL = tokC + start;
  const float2* wgtL = wC + start;

  // ---- staging sources ----
  const int s = lane & 3;
  const int rA0 = w * 32 + (lane >> 2);
  const int rA1 = rA0 + 16;
  const int gA0 = s ^ ((rA0 >> 1) & 3);
  const int gA1 = s ^ ((rA1 >> 1) & 3);
  const int tA0 = tokL[rA0 < ce ? rA0 : ce - 1];
  const int tA1 = tokL[rA1 < ce ? rA1 : ce - 1];
  const char* aSrc0 = (const char*)(xb + (size_t)tA0 * LDIM) + gA0 * 16;
  const char* aSrc1 = (const char*)(xb + (size_t)tA1 * LDIM) + gA1 * 16;
  const int rB = w * 16 + (lane >> 2);           // 0..127
  const int gB = s ^ ((rB >> 1) & 3);
  const int colB = colTile * BN + rB;
  const char* bSrcLo = (const char*)(wb + ((size_t)lo * ODIM + colB) * LDIM) + gB * 16;
  const char* bSrcHi = (const char*)(wb + ((size_t)hi * ODIM + colB) * LDIM) + gB * 16;

  // ---- ds_read offsets (shorts) ----
  int offA[8], offB[2];
#pragma unroll
  for (int fr = 0; fr < 8; ++fr) {
    const int r = wm * 128 + fr * 16 + (lane & 15);
    offA[fr] = r * BK + (((lane >> 4) ^ ((r >> 1) & 3)) * 8);
  }
#pragma unroll
  for (int fc = 0; fc < 2; ++fc) {
    const int r = wn * 32 + fc * 16 + (lane & 15);
    offB[fc] = r * BK + (((lane >> 4) ^ ((r >> 1) & 3)) * 8);
  }

  auto stage = [&](int b, int kt) {
    const int kb = kt * 64;  // bytes
    gload_lds16(aSrc0 + kb, &ldsA[b][w * 1024]);
    gload_lds16(aSrc1 + kb, &ldsA[b][w * 1024 + 512]);
    gload_lds16(bSrcLo + kb, &ldsB[b][w * 512]);
    gload_lds16(bSrcHi + kb, &ldsB[b][4096 + w * 512]);
  };

  f32x4 acc[2][8][2] = {};

  // ---- prologue: stage tiles 0,1 into bufs 0,1; certify tile 0 ----
  stage(0, 0); stage(1, 1);
  asm volatile("s_waitcnt vmcnt(4)" ::: "memory");   // stage 0 complete
  __builtin_amdgcn_s_barrier();

  int buf = 0;
#pragma unroll 1
  for (int kt = 0; kt < NKT; ++kt) {
    const unsigned short* As = &ldsA[buf][0];
    const unsigned short* Bs = &ldsB[buf][0];
    bf16x8 af[8], bl0, bl1, bh0, bh1;
#pragma unroll
    for (int fr = 0; fr < 8; ++fr) af[fr] = *(const bf16x8*)(As + offA[fr]);
    bl0 = *(const bf16x8*)(Bs + offB[0]);
    bl1 = *(const bf16x8*)(Bs + offB[1]);
    bh0 = *(const bf16x8*)(Bs + 4096 + offB[0]);
    bh1 = *(const bf16x8*)(Bs + 4096 + offB[1]);

    // stage tile kt+2 into the buffer read at body kt-1 (reads published there)
    int sb = buf + 2; if (sb > 2) sb -= 3;
    stage(sb, kt + 2 < NKT ? kt + 2 : NKT - 1);

    __builtin_amdgcn_s_setprio(1);
#pragma unroll
    for (int fr = 0; fr < 8; ++fr) {
      acc[0][fr][0] = __builtin_amdgcn_mfma_f32_16x16x32_bf16(af[fr], bl0, acc[0][fr][0], 0, 0, 0);
      acc[0][fr][1] = __builtin_amdgcn_mfma_f32_16x16x32_bf16(af[fr], bl1, acc[0][fr][1], 0, 0, 0);
      acc[1][fr][0] = __builtin_amdgcn_mfma_f32_16x16x32_bf16(af[fr], bh0, acc[1][fr][0], 0, 0, 0);
      acc[1][fr][1] = __builtin_amdgcn_mfma_f32_16x16x32_bf16(af[fr], bh1, acc[1][fr][1], 0, 0, 0);
    }
    __builtin_amdgcn_s_setprio(0);

    asm volatile("s_waitcnt lgkmcnt(0)" ::: "memory");  // all my reads of buf done
    asm volatile("s_waitcnt vmcnt(4)" ::: "memory");    // stage(kt+1) complete
    __builtin_amdgcn_s_barrier();                       // publish both
    buf = (buf == 2) ? 0 : buf + 1;
  }

  // ---- epilogue: store-once ----
  int cols[2]; float bLo[2], bHi[2];
#pragma unroll
  for (int fc = 0; fc < 2; ++fc) {
    cols[fc] = colTile * BN + wn * 32 + fc * 16 + (lane & 15);
    bLo[fc] = bias[lo * ODIM + cols[fc]];
    bHi[fc] = bias[hi * ODIM + cols[fc]];
  }
#pragma unroll
  for (int fr = 0; fr < 8; ++fr) {
#pragma unroll
    for (int rr = 0; rr < 4; ++rr) {
      const int row = wm * 128 + fr * 16 + (lane >> 4) * 4 + rr;
      if (row < ce) {
        const int tok = tokL[row];
        const float2 ww = wgtL[row];
        float* orow = out + (size_t)tok * ODIM;
#pragma unroll
        for (int fc = 0; fc < 2; ++fc)
          orow[cols[fc]] = ww.x * (acc[0][fr][fc][rr] + bLo[fc]) +
                           ww.y * (acc[1][fr][fc][rr] + bHi[fc]);
      }
    }
  }
}

// ---------------- emergency fallback (ws too small): slow but correct ----------------
__global__ __launch_bounds__(256) void naive_moe(
    const float* __restrict__ x, const float* __restrict__ gate,
    const float* __restrict__ ew, const float* __restrict__ eb,
    float* __restrict__ out, int T)
{
  const int tok = blockIdx.x, tid = threadIdx.x;
  __shared__ float xs[LDIM];
  __shared__ float logits[E_EXP];
  __shared__ float sw1, sw2; __shared__ int si1, si2;
  for (int i = tid; i < LDIM; i += 256) xs[i] = x[(size_t)tok * LDIM + i];
  __syncthreads();
  const int wid = tid >> 6, lane = tid & 63;
  for (int e = wid; e < E_EXP; e += 4) {
    float a = 0.f;
    for (int i = lane; i < LDIM; i += 64) a += xs[i] * gate[e * LDIM + i];
    for (int off = 32; off >= 1; off >>= 1) a += __shfl_xor(a, off, 64);
    if (lane == 0) logits[e] = a;
  }
  __syncthreads();
  if (tid == 0) {
    int i1 = 0; float m1 = logits[0];
    for (int e = 1; e < E_EXP; ++e) if (logits[e] > m1) { m1 = logits[e]; i1 = e; }
    int i2 = -1; float m2 = -1e30f;
    for (int e = 0; e < E_EXP; ++e) if (e != i1 && logits[e] > m2) { m2 = logits[e]; i2 = e; }
    float s = 0.f;
    for (int e = 0; e < E_EXP; ++e) s += __expf(logits[e] - m1);
    si1 = i1; si2 = i2; sw1 = 1.f / s; sw2 = __expf(m2 - m1) / s;
  }
  __syncthreads();
  const int i1 = si1, i2 = si2; const float w1 = sw1, w2 = sw2;
  for (int o = tid; o < ODIM; o += 256) {
    float a1 = 0.f, a2 = 0.f;
    const float* p1 = ew + ((size_t)i1 * ODIM + o) * LDIM;
    const float* p2 = ew + ((size_t)i2 * ODIM + o) * LDIM;
    for (int l = 0; l < LDIM; ++l) { a1 += xs[l] * p1[l]; a2 += xs[l] * p2[l]; }
    out[(size_t)tok * ODIM + o] =
        w1 * (a1 + eb[i1 * ODIM + o]) + w2 * (a2 + eb[i2 * ODIM + o]);
  }
}

extern "C" void kernel_launch(void* const* d_in, const int* in_sizes, int n_in,
                              void* d_out, int out_size, void* d_ws, size_t ws_size,
                              hipStream_t stream) {
  const float* x    = (const float*)d_in[0];
  const float* gate = (const float*)d_in[1];
  const float* ew   = (const float*)d_in[2];
  const float* eb   = (const float*)d_in[3];
  float* out = (float*)d_out;
  const int T = in_sizes[0] / LDIM;  // 32768
  const int NB = (T + 2047) / 2048; // 16

  // ws layout (aligned regions)
  const size_t offSel   = 0;                                   // T ints
  const size_t offPw    = offSel + (size_t)T * 4;              // T float2
  const size_t offHist  = offPw + (size_t)T * 8;               // NB*64 ints
  const size_t offBBase = offHist + (size_t)NB * NPAIR * 4;    // NB*64 ints
  const size_t offDesc  = offBBase + (size_t)NB * NPAIR * 4;   // MAXRT int4
  const size_t offMeta  = offDesc + (size_t)MAXRT * 16;        // 1 int (pad 256)
  const size_t offTokC  = offMeta + 256;                       // T ints
  const size_t offWC    = offTokC + (size_t)T * 4;             // T float2
  const size_t offXb    = offWC + (size_t)T * 8;               // T*L bf16 = 64MB
  const size_t offWb    = offXb + (size_t)T * LDIM * 2;        // 16MB
  const size_t need     = offWb + (size_t)E_EXP * ODIM * LDIM * 2;  // ~81MB

  if (ws_size < need) {
    naive_moe<<<T, 256, 0, stream>>>(x, gate, ew, eb, out, T);
    return;
  }

  char* ws = (char*)d_ws;

  route_conv_kernel<<<CONV_BLOCKS + (T + 15) / 16, 256, 0, stream>>>(
      x, gate, ew, (unsigned short*)(ws + offXb), (unsigned short*)(ws + offWb),
      (int*)(ws + offSel), (float2*)(ws + offPw), T);

  hist_kernel<<<NB, 256, 0, stream>>>(
      (const int*)(ws + offSel), (int*)(ws + offHist), T);

  finalize_kernel<<<1, 64, 0, stream>>>(
      (const int*)(ws + offHist), NB, (int*)(ws + offBBase),
      (int4*)(ws + offDesc), (int*)(ws + offMeta));

  scatter_kernel<<<NB, 256, 0, stream>>>(
      (const int*)(ws + offSel), (const float2*)(ws + offPw),
      (const int*)(ws + offBBase), (int*)(ws + offTokC),
      (float2*)(ws + offWC), T);

  moe_gemm_pair<<<GEMM_GRID, 512, 0, stream>>>(
      (const unsigned short*)(ws + offXb), (const unsigned short*)(ws + offWb),
      eb, (const int4*)(ws + offDesc), (const int*)(ws + offMeta),
      (const int*)(ws + offTokC), (const float2*)(ws + offWC), out);
}